// Round 3
// baseline (149.015 us; speedup 1.0000x reference)
//
#include <hip/hip_runtime.h>
#include <math.h>

#define N_ROWS 1024
#define RANK   8
#define M_COLS 4096
#define ROWS_PER_BLOCK 8

// Static device scratch (module-load allocated; fully overwritten every call
// before it is read — no hipMalloc, graph-capture safe, no cross-call state).
__device__ float2 g_Y[RANK * M_COLS];     // [8][64][64] complex, 256 KB
__device__ float2 g_Hft[RANK * M_COLS];   // [8][4096]   complex, 256 KB

__device__ __forceinline__ float softplus_f(float x) {
    if (x > 20.0f)  return x;
    if (x < -20.0f) return __expf(x);
    return log1pf(__expf(x));
}

// ---------------------------------------------------------------------------
// Stage A: Y[d][k0][m0] = sum_{k1<64} softplus(H[d, 64*k1 + k0]) * e^{-2pi i k1 m0 / 64}
// 32768 threads, t = ((d*64 + k0)*64 + m0)
// ---------------------------------------------------------------------------
__global__ void dft_stageA(const float* __restrict__ H) {
    int t  = blockIdx.x * blockDim.x + threadIdx.x;
    int m0 = t & 63;
    int k0 = (t >> 6) & 63;
    int d  = t >> 12;
    const float* Hrow = H + d * M_COLS;
    float accr = 0.0f, acci = 0.0f;
    const float step = -6.28318530717958647692f / 64.0f;
    for (int k1 = 0; k1 < 64; ++k1) {
        float v = softplus_f(Hrow[(k1 << 6) + k0]);   // same addr across lanes of a row-group
        int idx = (k1 * m0) & 63;
        float ang = step * (float)idx;
        float s, c;
        __sincosf(ang, &s, &c);
        accr += v * c;
        acci += v * s;
    }
    g_Y[t] = make_float2(accr, acci);
}

// ---------------------------------------------------------------------------
// Stage B: Hft[d][m] = sum_{k0<64} Y[d][k0][m & 63] * e^{-2pi i k0 m / 4096}
// 32768 threads, t = d*4096 + m
// ---------------------------------------------------------------------------
__global__ void dft_stageB() {
    int t  = blockIdx.x * blockDim.x + threadIdx.x;
    int m  = t & 4095;
    int d  = t >> 12;
    int m0 = m & 63;
    const float2* Yd = g_Y + (d << 12);
    float accr = 0.0f, acci = 0.0f;
    const float step = -6.28318530717958647692f / 4096.0f;
    for (int k0 = 0; k0 < 64; ++k0) {
        float2 y = Yd[(k0 << 6) + m0];
        int idx = (k0 * m) & 4095;
        float ang = step * (float)idx;
        float s, c;
        __sincosf(ang, &s, &c);
        accr += y.x * c - y.y * s;
        acci += y.x * s + y.y * c;
    }
    g_Hft[t] = make_float2(accr, acci);
}

// ---------------------------------------------------------------------------
// Main: Re(V)[n,m] = sum_d softplus(W[n,d]) * Re( e^{-2pi i tau f_m} * Hft[d,m] )
//                  = sum_d w * (cos(a)*hr - sin(a)*hi),  a = -2pi*tau*m/M
// Output is float32 real part only (harness stores ref as float32 = real part).
// ---------------------------------------------------------------------------
__global__ void shiftnmf_main(const float* __restrict__ W,
                              const float* __restrict__ tau,
                              float* __restrict__ out) {
    int m  = blockIdx.x * blockDim.x + threadIdx.x;      // 0..4095
    int n0 = blockIdx.y * ROWS_PER_BLOCK;

    float hr[RANK], hi[RANK];
    #pragma unroll
    for (int d = 0; d < RANK; ++d) {
        float2 h = g_Hft[d * M_COLS + m];
        hr[d] = h.x;
        hi[d] = h.y;
    }

    float fm = (float)m * (1.0f / (float)M_COLS);
    const float neg2pi = -6.28318530717958647692f;

    #pragma unroll
    for (int r = 0; r < ROWS_PER_BLOCK; ++r) {
        int n = n0 + r;
        float accr = 0.0f;
        #pragma unroll
        for (int d = 0; d < RANK; ++d) {
            float w  = softplus_f(W[n * RANK + d]);      // block-uniform -> scalarized
            float tv = tau[n * RANK + d];
            float a  = neg2pi * tv * fm;
            float s, c;
            __sincosf(a, &s, &c);
            accr += w * (c * hr[d] - s * hi[d]);
        }
        out[n * M_COLS + m] = accr;
    }
}

extern "C" void kernel_launch(void* const* d_in, const int* in_sizes, int n_in,
                              void* d_out, int out_size, void* d_ws, size_t ws_size,
                              hipStream_t stream) {
    const float* W   = (const float*)d_in[0];   // [1024, 8]
    const float* H   = (const float*)d_in[1];   // [8, 4096]
    const float* tau = (const float*)d_in[2];   // [1024, 8]

    dft_stageA<<<dim3(RANK * M_COLS / 256), dim3(256), 0, stream>>>(H);
    dft_stageB<<<dim3(RANK * M_COLS / 256), dim3(256), 0, stream>>>();

    dim3 grid(M_COLS / 256, N_ROWS / ROWS_PER_BLOCK);
    shiftnmf_main<<<grid, dim3(256), 0, stream>>>(W, tau, (float*)d_out);
}

// Round 4
// 30.520 us; speedup vs baseline: 4.8825x; 4.8825x over previous
//
#include <hip/hip_runtime.h>
#include <math.h>

#define N_ROWS 1024
#define RANK   8
#define M_COLS 4096
#define ROWS_PER_BLOCK 8

// Static device scratch (module-load allocated; fully overwritten every call
// before it is read — no hipMalloc, graph-capture safe, no cross-call state).
__device__ float  g_Hs [RANK * M_COLS];   // softplus(H), 128 KB
__device__ float  g_Wp [N_ROWS * RANK];   // softplus(W), 32 KB
__device__ float2 g_Y  [RANK * M_COLS];   // stage-A intermediate, 256 KB
__device__ float2 g_Hft[RANK * M_COLS];   // full FFT of softplus(H), 256 KB

__device__ __forceinline__ float softplus_f(float x) {
    if (x > 20.0f)  return x;
    if (x < -20.0f) return __expf(x);
    return log1pf(__expf(x));
}

// hw trig: v_sin_f32/v_cos_f32 compute sin/cos(2*pi*x), x in revolutions.
__device__ __forceinline__ float sin_rev(float x) { return __builtin_amdgcn_sinf(x); }
__device__ __forceinline__ float cos_rev(float x) { return __builtin_amdgcn_cosf(x); }
__device__ __forceinline__ float fract_f(float x) { return __builtin_amdgcn_fractf(x); }

// ---------------------------------------------------------------------------
// Prep: g_Hs = softplus(H) (32768 elems), g_Wp = softplus(W) (8192 elems)
// ---------------------------------------------------------------------------
__global__ void prep_softplus(const float* __restrict__ H,
                              const float* __restrict__ W) {
    int t = blockIdx.x * blockDim.x + threadIdx.x;   // 0..32767
    g_Hs[t] = softplus_f(H[t]);
    if (t < N_ROWS * RANK) g_Wp[t] = softplus_f(W[t]);
}

// ---------------------------------------------------------------------------
// Stage A: Y[d][k0][m0] = sum_{k1<64} Hs[d, 64*k1 + k0] * e^{-2pi i k1 m0 / 64}
// angle in revolutions: (k1*m0 mod 64)/64
// ---------------------------------------------------------------------------
__global__ void dft_stageA() {
    int t  = blockIdx.x * blockDim.x + threadIdx.x;
    int m0 = t & 63;
    int k0 = (t >> 6) & 63;
    int d  = t >> 12;
    const float* Hrow = g_Hs + d * M_COLS;
    float accr = 0.0f, acci = 0.0f;
    for (int k1 = 0; k1 < 64; ++k1) {
        float v   = Hrow[(k1 << 6) + k0];            // wave-broadcast load
        float rev = (float)((k1 * m0) & 63) * (1.0f / 64.0f);
        float s = sin_rev(rev), c = cos_rev(rev);
        accr = fmaf(v,  c, accr);                    // e^{-i t} = cos - i sin
        acci = fmaf(v, -s, acci);
    }
    g_Y[t] = make_float2(accr, acci);
}

// ---------------------------------------------------------------------------
// Stage B: Hft[d][m] = sum_{k0<64} Y[d][k0][m & 63] * e^{-2pi i k0 m / 4096}
// ---------------------------------------------------------------------------
__global__ void dft_stageB() {
    int t  = blockIdx.x * blockDim.x + threadIdx.x;
    int m  = t & 4095;
    int d  = t >> 12;
    int m0 = m & 63;
    const float2* Yd = g_Y + (d << 12);
    float accr = 0.0f, acci = 0.0f;
    for (int k0 = 0; k0 < 64; ++k0) {
        float2 y  = Yd[(k0 << 6) + m0];
        float rev = (float)((k0 * m) & 4095) * (1.0f / 4096.0f);
        float s = sin_rev(rev), c = cos_rev(rev);
        // (yr + i yi)(c - i s): re = yr*c + yi*s ; im = yi*c - yr*s
        accr = fmaf(y.x, c, fmaf( y.y, s, accr));
        acci = fmaf(y.y, c, fmaf(-y.x, s, acci));
    }
    g_Hft[t] = make_float2(accr, acci);
}

// ---------------------------------------------------------------------------
// Main: Re(V)[n,m] = sum_d Wp[n,d] * ( cos(2pi r)*hr + sin(2pi r)*hi ),
//       r = tau[n,d]*m/M   (since e^{-2pi i r}*(hr+i hi) has real part
//       cos*hr + sin*hi)
// ---------------------------------------------------------------------------
__global__ void shiftnmf_main(const float* __restrict__ tau,
                              float* __restrict__ out) {
    int m  = blockIdx.x * blockDim.x + threadIdx.x;      // 0..4095
    int n0 = blockIdx.y * ROWS_PER_BLOCK;

    float hr[RANK], hi[RANK];
    #pragma unroll
    for (int d = 0; d < RANK; ++d) {
        float2 h = g_Hft[d * M_COLS + m];
        hr[d] = h.x;
        hi[d] = h.y;
    }

    float fm = (float)m * (1.0f / (float)M_COLS);

    #pragma unroll
    for (int r = 0; r < ROWS_PER_BLOCK; ++r) {
        int n = n0 + r;
        float accr = 0.0f;
        #pragma unroll
        for (int d = 0; d < RANK; ++d) {
            float w   = g_Wp[n * RANK + d];              // block-uniform -> s_load
            float tv  = tau [n * RANK + d];              // block-uniform -> s_load
            float rev = fract_f(tv * fm);
            float s = sin_rev(rev), c = cos_rev(rev);
            float t = c * hr[d];
            t = fmaf(s, hi[d], t);
            accr = fmaf(w, t, accr);
        }
        out[n * M_COLS + m] = accr;
    }
}

extern "C" void kernel_launch(void* const* d_in, const int* in_sizes, int n_in,
                              void* d_out, int out_size, void* d_ws, size_t ws_size,
                              hipStream_t stream) {
    const float* W   = (const float*)d_in[0];   // [1024, 8]
    const float* H   = (const float*)d_in[1];   // [8, 4096]
    const float* tau = (const float*)d_in[2];   // [1024, 8]

    prep_softplus<<<dim3(RANK * M_COLS / 256), dim3(256), 0, stream>>>(H, W);
    dft_stageA  <<<dim3(RANK * M_COLS / 256), dim3(256), 0, stream>>>();
    dft_stageB  <<<dim3(RANK * M_COLS / 256), dim3(256), 0, stream>>>();

    dim3 grid(M_COLS / 256, N_ROWS / ROWS_PER_BLOCK);
    shiftnmf_main<<<grid, dim3(256), 0, stream>>>(tau, (float*)d_out);
}

// Round 5
// 28.489 us; speedup vs baseline: 5.2306x; 1.0713x over previous
//
#include <hip/hip_runtime.h>
#include <math.h>

#define N_ROWS 1024
#define RANK   8
#define M_COLS 4096
#define ROWS_PER_BLOCK 8

// Static device scratch (module-load allocated; fully overwritten every call
// before it is read — no hipMalloc, graph-capture safe, no cross-call state).
__device__ float  g_Wp [N_ROWS * RANK];   // softplus(W), 32 KB
__device__ float2 g_Hft[RANK * M_COLS];   // full FFT of softplus(H), 256 KB

__device__ __forceinline__ float softplus_f(float x) {
    if (x > 20.0f)  return x;
    if (x < -20.0f) return __expf(x);
    return log1pf(__expf(x));
}

// hw trig: v_sin_f32/v_cos_f32 compute sin/cos(2*pi*x), x in revolutions.
__device__ __forceinline__ float sin_rev(float x) { return __builtin_amdgcn_sinf(x); }
__device__ __forceinline__ float cos_rev(float x) { return __builtin_amdgcn_cosf(x); }
__device__ __forceinline__ float fract_f(float x) { return __builtin_amdgcn_fractf(x); }

// ---------------------------------------------------------------------------
// Fused FFT kernel: softplus(H) + 64x64 Cooley-Tukey DFT -> g_Hft.
// 128 blocks x 256 threads. Block b: d = b>>4, m0-range = [(b&15)*4, +4).
//   phase 0: (blocks 0..31) side-job: g_Wp = softplus(W), 256 elems/block
//   phase 1: coop load softplus(H[d,:]) -> sHs[4096] (each elem exactly once)
//   phase 2: stage A: Y[k0][j] = sum_k1 sHs[k1*64+k0] * e^{-2pi i k1 m0/64}
//   phase 3: stage B: Hft[d][m1*64+m0] = sum_k0 Y[k0][j] * e^{-2pi i k0 m/4096}
// ---------------------------------------------------------------------------
__global__ void fft_fused(const float* __restrict__ H,
                          const float* __restrict__ W) {
    __shared__ float  sHs[M_COLS];        // 16 KB
    __shared__ float2 sY[4 * 64];         // [j][k0], 2 KB

    int tid = threadIdx.x;
    int d   = blockIdx.x >> 4;
    int m0b = (blockIdx.x & 15) << 2;

    if (blockIdx.x < 32) {                // Wp side-job, no dependency
        int t = blockIdx.x * 256 + tid;   // < 8192
        g_Wp[t] = softplus_f(W[t]);
    }

    const float* Hrow = H + d * M_COLS;
    for (int i = tid; i < M_COLS; i += 256)
        sHs[i] = softplus_f(Hrow[i]);
    __syncthreads();

    {   // stage A: thread = (k0 = tid&63, j = tid>>6), m0 = m0b + j
        int k0 = tid & 63, j = tid >> 6;
        int m0 = m0b + j;
        float ar = 0.0f, ai = 0.0f;
        for (int k1 = 0; k1 < 64; ++k1) {
            float v   = sHs[(k1 << 6) + k0];           // 2-way bank alias: free
            float rev = (float)((k1 * m0) & 63) * (1.0f / 64.0f);
            float s = sin_rev(rev), c = cos_rev(rev);
            ar = fmaf(v,  c, ar);                      // e^{-i t} = cos - i sin
            ai = fmaf(v, -s, ai);
        }
        sY[(j << 6) + k0] = make_float2(ar, ai);
    }
    __syncthreads();

    {   // stage B: thread = (m1 = tid&63, j = tid>>6), m = m1*64 + m0b + j
        int m1 = tid & 63, j = tid >> 6;
        int m  = (m1 << 6) + m0b + j;
        float ar = 0.0f, ai = 0.0f;
        for (int k0 = 0; k0 < 64; ++k0) {
            float2 y  = sY[(j << 6) + k0];             // wave-broadcast read
            float rev = (float)((k0 * m) & 4095) * (1.0f / 4096.0f);
            float s = sin_rev(rev), c = cos_rev(rev);
            // (yr + i yi)(c - i s): re = yr*c + yi*s ; im = yi*c - yr*s
            ar = fmaf(y.x, c, fmaf( y.y, s, ar));
            ai = fmaf(y.y, c, fmaf(-y.x, s, ai));
        }
        g_Hft[d * M_COLS + m] = make_float2(ar, ai);
    }
}

// ---------------------------------------------------------------------------
// Main: Re(V)[n,m] = sum_d Wp[n,d] * ( cos(2pi r)*hr + sin(2pi r)*hi ),
//       r = tau[n,d]*m/M
// ---------------------------------------------------------------------------
__global__ void shiftnmf_main(const float* __restrict__ tau,
                              float* __restrict__ out) {
    int m  = blockIdx.x * blockDim.x + threadIdx.x;      // 0..4095
    int n0 = blockIdx.y * ROWS_PER_BLOCK;

    float hr[RANK], hi[RANK];
    #pragma unroll
    for (int d = 0; d < RANK; ++d) {
        float2 h = g_Hft[d * M_COLS + m];
        hr[d] = h.x;
        hi[d] = h.y;
    }

    float fm = (float)m * (1.0f / (float)M_COLS);

    #pragma unroll
    for (int r = 0; r < ROWS_PER_BLOCK; ++r) {
        int n = n0 + r;
        float accr = 0.0f;
        #pragma unroll
        for (int d = 0; d < RANK; ++d) {
            float w   = g_Wp[n * RANK + d];              // block-uniform
            float tv  = tau [n * RANK + d];              // block-uniform
            float rev = fract_f(tv * fm);
            float s = sin_rev(rev), c = cos_rev(rev);
            float t = c * hr[d];
            t = fmaf(s, hi[d], t);
            accr = fmaf(w, t, accr);
        }
        out[n * M_COLS + m] = accr;
    }
}

extern "C" void kernel_launch(void* const* d_in, const int* in_sizes, int n_in,
                              void* d_out, int out_size, void* d_ws, size_t ws_size,
                              hipStream_t stream) {
    const float* W   = (const float*)d_in[0];   // [1024, 8]
    const float* H   = (const float*)d_in[1];   // [8, 4096]
    const float* tau = (const float*)d_in[2];   // [1024, 8]

    fft_fused<<<dim3(RANK * 16), dim3(256), 0, stream>>>(H, W);

    dim3 grid(M_COLS / 256, N_ROWS / ROWS_PER_BLOCK);
    shiftnmf_main<<<grid, dim3(256), 0, stream>>>(tau, (float*)d_out);
}

// Round 6
// 25.245 us; speedup vs baseline: 5.9028x; 1.1285x over previous
//
#include <hip/hip_runtime.h>
#include <math.h>

#define N_ROWS 1024
#define RANK   8
#define M_COLS 4096

#define R_ROWS   4      // n-rows per thread (Hft reuse)
#define T_PTS    8      // m-points per thread (trig amortization)
#define M_STRIDE 512    // point spacing (keeps loads/stores coalesced)

// Static device scratch (module-load allocated; fully overwritten every call
// before it is read — graph-capture safe, no cross-call state).
__device__ float  g_Wp [N_ROWS * RANK];   // softplus(W), 32 KB
__device__ float2 g_Hft[RANK * M_COLS];   // full FFT of softplus(H), 256 KB

__device__ __forceinline__ float softplus_f(float x) {
    if (x > 20.0f)  return x;
    if (x < -20.0f) return __expf(x);
    return log1pf(__expf(x));
}
// hw trig: v_sin_f32/v_cos_f32 compute sin/cos(2*pi*x), x in revolutions.
__device__ __forceinline__ float sin_rev(float x) { return __builtin_amdgcn_sinf(x); }
__device__ __forceinline__ float cos_rev(float x) { return __builtin_amdgcn_cosf(x); }
__device__ __forceinline__ float fract_f(float x) { return __builtin_amdgcn_fractf(x); }

// ---------------------------------------------------------------------------
// Fused FFT: softplus(H) + 64x64 Cooley-Tukey DFT -> g_Hft.
// 128 blocks x 256 threads; block b: d = b>>4, m0 range [(b&15)*4, +4).
// All twiddles via exact-init complex-rotation recurrence (tw=(1,0), 64 steps).
// ---------------------------------------------------------------------------
__global__ void fft_fused(const float* __restrict__ H,
                          const float* __restrict__ W) {
    __shared__ float  sHs[M_COLS];        // 16 KB
    __shared__ float2 sY[4 * 64];         // [j][k0], 2 KB

    int tid = threadIdx.x;
    int d   = blockIdx.x >> 4;
    int m0b = (blockIdx.x & 15) << 2;

    if (blockIdx.x < 32) {                // Wp side-job (no dependency)
        int t = blockIdx.x * 256 + tid;   // < 8192
        g_Wp[t] = softplus_f(W[t]);
    }

    // softplus(H row) -> LDS, float4-vectorized
    const float4* Hrow4 = (const float4*)(H + d * M_COLS);
    #pragma unroll
    for (int p = 0; p < 4; ++p) {
        int i = p * 256 + tid;            // 1024 float4 per row
        float4 h4 = Hrow4[i];
        sHs[i*4+0] = softplus_f(h4.x);
        sHs[i*4+1] = softplus_f(h4.y);
        sHs[i*4+2] = softplus_f(h4.z);
        sHs[i*4+3] = softplus_f(h4.w);
    }
    __syncthreads();

    {   // stage A: thread = (k0 = tid&63, j = tid>>6), m0 = m0b + j
        // Y[k0][j] = sum_k1 sHs[k1*64+k0] * e^{-2pi i k1 m0/64}
        int k0 = tid & 63, j = tid >> 6;
        int m0 = m0b + j;
        float mrev = (float)m0 * (1.0f / 64.0f);
        float rr =  cos_rev(mrev);
        float ri = -sin_rev(mrev);        // step = e^{-2pi i m0/64}
        float twr = 1.0f, twi = 0.0f;
        float ar = 0.0f, ai = 0.0f;
        #pragma unroll
        for (int k1 = 0; k1 < 64; ++k1) {
            float v = sHs[(k1 << 6) + k0];            // 2-way bank alias: free
            ar = fmaf(v, twr, ar);
            ai = fmaf(v, twi, ai);
            float nr = fmaf(twr, rr, -(twi * ri));    // tw *= rot
            twi      = fmaf(twr, ri,   twi * rr);
            twr = nr;
        }
        sY[(j << 6) + k0] = make_float2(ar, ai);
    }
    __syncthreads();

    {   // stage B: thread = (m1 = tid&63, j = tid>>6), m = m1*64 + m0b + j
        // Hft[d][m] = sum_k0 Y[k0][j] * e^{-2pi i k0 m/4096}
        int m1 = tid & 63, j = tid >> 6;
        int m  = (m1 << 6) + m0b + j;
        float mrev = (float)m * (1.0f / 4096.0f);
        float rr =  cos_rev(mrev);
        float ri = -sin_rev(mrev);        // step = e^{-2pi i m/4096}
        float twr = 1.0f, twi = 0.0f;
        float ar = 0.0f, ai = 0.0f;
        #pragma unroll
        for (int k0 = 0; k0 < 64; ++k0) {
            float2 y = sY[(j << 6) + k0];             // wave-broadcast read
            ar = fmaf(y.x, twr, fmaf(-y.y, twi, ar)); // Re(y*tw)
            ai = fmaf(y.x, twi, fmaf( y.y, twr, ai)); // Im(y*tw)
            float nr = fmaf(twr, rr, -(twi * ri));    // tw *= rot
            twi      = fmaf(twr, ri,   twi * rr);
            twr = nr;
        }
        g_Hft[d * M_COLS + m] = make_float2(ar, ai);
    }
}

// ---------------------------------------------------------------------------
// Main: Re(V)[n,m] = sum_d Wp * ( cos(2pi r)*hr + sin(2pi r)*hi ), r = tau*m/M.
// Thread: R_ROWS n-rows x T_PTS m-points (stride M_STRIDE).
// Per (n,d): 4 trans ops total; per point: 2 FMA accum + 4 FMA rotation.
// ---------------------------------------------------------------------------
__global__ void shiftnmf_main(const float* __restrict__ tau,
                              float* __restrict__ out) {
    int tid = threadIdx.x;
    int m0  = blockIdx.x * 256 + tid;     // 0..511
    int n0  = blockIdx.y * R_ROWS;

    float acc[R_ROWS][T_PTS];
    #pragma unroll
    for (int r = 0; r < R_ROWS; ++r)
        #pragma unroll
        for (int j = 0; j < T_PTS; ++j) acc[r][j] = 0.0f;

    float fm0 = (float)m0 * (1.0f / (float)M_COLS);

    #pragma unroll
    for (int d = 0; d < RANK; ++d) {
        float uwr[R_ROWS], uwi[R_ROWS], vr[R_ROWS], vi[R_ROWS];
        #pragma unroll
        for (int r = 0; r < R_ROWS; ++r) {
            int n    = n0 + r;
            float w  = g_Wp[n * RANK + d];            // block-uniform -> s_load
            float tv = tau [n * RANK + d];            // block-uniform -> s_load
            float sv = fract_f(tv * ((float)M_STRIDE / (float)M_COLS));
            vr[r] = cos_rev(sv);                      // step = e^{+i 2pi tau*512/M}
            vi[r] = sin_rev(sv);
            float r0 = fract_f(tv * fm0);
            float c0 = cos_rev(r0), s0 = sin_rev(r0);
            uwr[r] = w * c0;                          // uw = w * e^{+i 2pi tau*m0/M}
            uwi[r] = w * s0;
        }
        const float2* hp = g_Hft + d * M_COLS + m0;
        #pragma unroll
        for (int j = 0; j < T_PTS; ++j) {
            float2 h = hp[j * M_STRIDE];              // coalesced, L2-resident
            #pragma unroll
            for (int r = 0; r < R_ROWS; ++r) {
                acc[r][j] = fmaf(uwr[r], h.x, fmaf(uwi[r], h.y, acc[r][j]));
                float nr = fmaf(uwr[r], vr[r], -(uwi[r] * vi[r]));  // uw *= v
                uwi[r]   = fmaf(uwr[r], vi[r],   uwi[r] * vr[r]);
                uwr[r]   = nr;
            }
        }
    }

    #pragma unroll
    for (int r = 0; r < R_ROWS; ++r) {
        float* op = out + (n0 + r) * M_COLS + m0;
        #pragma unroll
        for (int j = 0; j < T_PTS; ++j)
            op[j * M_STRIDE] = acc[r][j];
    }
}

extern "C" void kernel_launch(void* const* d_in, const int* in_sizes, int n_in,
                              void* d_out, int out_size, void* d_ws, size_t ws_size,
                              hipStream_t stream) {
    const float* W   = (const float*)d_in[0];   // [1024, 8]
    const float* H   = (const float*)d_in[1];   // [8, 4096]
    const float* tau = (const float*)d_in[2];   // [1024, 8]

    fft_fused<<<dim3(RANK * 16), dim3(256), 0, stream>>>(H, W);

    dim3 grid(M_COLS / (256 * T_PTS) * 256 / 256, N_ROWS / R_ROWS);  // (2, 256)
    shiftnmf_main<<<grid, dim3(256), 0, stream>>>(tau, (float*)d_out);
}

// Round 7
// 21.208 us; speedup vs baseline: 7.0265x; 1.1904x over previous
//
#include <hip/hip_runtime.h>
#include <math.h>

#define N_ROWS 1024
#define RANK   8
#define M_COLS 4096

#define R_ROWS   2      // n-rows per thread (Hft register reuse)
#define T_PTS    8      // m-points per thread (trig amortized by rotation)
#define M_STRIDE 512    // point spacing (coalesced loads/stores)

// Static device scratch (fully overwritten every call before read).
__device__ float  g_Wp [N_ROWS * RANK];   // softplus(W), 32 KB
__device__ float2 g_Hft[RANK * M_COLS];   // full FFT of softplus(H), 256 KB

// fast softplus: 2 trans + ~4 VALU. exact for x>20; inputs are ~N(0,1).
__device__ __forceinline__ float softplus_f(float x) {
    float t = __expf(x);                       // v_exp (e^x)
    float r = 0.69314718056f * __log2f(1.0f + t);
    return (x > 20.0f) ? x : r;
}
// hw trig: v_sin/v_cos compute sin/cos(2*pi*x), x in revolutions.
__device__ __forceinline__ float sin_rev(float x) { return __builtin_amdgcn_sinf(x); }
__device__ __forceinline__ float cos_rev(float x) { return __builtin_amdgcn_cosf(x); }
__device__ __forceinline__ float fract_f(float x) { return __builtin_amdgcn_fractf(x); }

// ---------------------------------------------------------------------------
// Fused FFT: softplus(H) + 64x64 Cooley-Tukey DFT -> g_Hft.
// 128 blocks x 256 threads; block b: d = b>>4, m0 range [(b&15)*4, +4).
// Twiddles via exact-init complex-rotation recurrence.
// ---------------------------------------------------------------------------
__global__ void fft_fused(const float* __restrict__ H,
                          const float* __restrict__ W) {
    __shared__ float  sHs[M_COLS];        // 16 KB
    __shared__ float2 sY[4 * 64];         // [j][k0], 2 KB

    int tid = threadIdx.x;
    int d   = blockIdx.x >> 4;
    int m0b = (blockIdx.x & 15) << 2;

    if (blockIdx.x < 32) {                // Wp side-job (no dependency)
        int t = blockIdx.x * 256 + tid;   // < 8192
        g_Wp[t] = softplus_f(W[t]);
    }

    const float4* Hrow4 = (const float4*)(H + d * M_COLS);
    #pragma unroll
    for (int p = 0; p < 4; ++p) {
        int i = p * 256 + tid;            // 1024 float4 per row
        float4 h4 = Hrow4[i];
        sHs[i*4+0] = softplus_f(h4.x);
        sHs[i*4+1] = softplus_f(h4.y);
        sHs[i*4+2] = softplus_f(h4.z);
        sHs[i*4+3] = softplus_f(h4.w);
    }
    __syncthreads();

    {   // stage A: thread = (k0 = tid&63, j = tid>>6), m0 = m0b + j
        int k0 = tid & 63, j = tid >> 6;
        int m0 = m0b + j;
        float mrev = (float)m0 * (1.0f / 64.0f);
        float rr =  cos_rev(mrev);
        float ri = -sin_rev(mrev);        // step = e^{-2pi i m0/64}
        float twr = 1.0f, twi = 0.0f;
        float ar = 0.0f, ai = 0.0f;
        #pragma unroll
        for (int k1 = 0; k1 < 64; ++k1) {
            float v = sHs[(k1 << 6) + k0];
            ar = fmaf(v, twr, ar);
            ai = fmaf(v, twi, ai);
            float nr = fmaf(twr, rr, -(twi * ri));
            twi      = fmaf(twr, ri,   twi * rr);
            twr = nr;
        }
        sY[(j << 6) + k0] = make_float2(ar, ai);
    }
    __syncthreads();

    {   // stage B: thread = (m1 = tid&63, j = tid>>6), m = m1*64 + m0b + j
        int m1 = tid & 63, j = tid >> 6;
        int m  = (m1 << 6) + m0b + j;
        float mrev = (float)m * (1.0f / 4096.0f);
        float rr =  cos_rev(mrev);
        float ri = -sin_rev(mrev);        // step = e^{-2pi i m/4096}
        float twr = 1.0f, twi = 0.0f;
        float ar = 0.0f, ai = 0.0f;
        #pragma unroll
        for (int k0 = 0; k0 < 64; ++k0) {
            float2 y = sY[(j << 6) + k0];
            ar = fmaf(y.x, twr, fmaf(-y.y, twi, ar));
            ai = fmaf(y.x, twi, fmaf( y.y, twr, ai));
            float nr = fmaf(twr, rr, -(twi * ri));
            twi      = fmaf(twr, ri,   twi * rr);
            twr = nr;
        }
        g_Hft[d * M_COLS + m] = make_float2(ar, ai);
    }
}

// ---------------------------------------------------------------------------
// Main: Re(V)[n,m] = sum_d Wp * ( cos(2pi r)*hr + sin(2pi r)*hi ), r = tau*m/M.
// Thread: R_ROWS=2 rows x T_PTS=8 points (stride 512).
// grid (2, 512) = 1024 blocks = 4096 waves = 4 waves/SIMD (latency hiding).
// ---------------------------------------------------------------------------
__global__ void shiftnmf_main(const float* __restrict__ tau,
                              float* __restrict__ out) {
    int tid = threadIdx.x;
    int m0  = blockIdx.x * 256 + tid;     // 0..511
    int n0  = blockIdx.y * R_ROWS;

    float acc[R_ROWS][T_PTS];
    #pragma unroll
    for (int r = 0; r < R_ROWS; ++r)
        #pragma unroll
        for (int j = 0; j < T_PTS; ++j) acc[r][j] = 0.0f;

    float fm0 = (float)m0 * (1.0f / (float)M_COLS);

    #pragma unroll
    for (int d = 0; d < RANK; ++d) {
        float uwr[R_ROWS], uwi[R_ROWS], vr[R_ROWS], vi[R_ROWS];
        #pragma unroll
        for (int r = 0; r < R_ROWS; ++r) {
            int n    = n0 + r;
            float w  = g_Wp[n * RANK + d];            // block-uniform -> s_load
            float tv = tau [n * RANK + d];            // block-uniform -> s_load
            float sv = fract_f(tv * ((float)M_STRIDE / (float)M_COLS));
            vr[r] = cos_rev(sv);                      // step = e^{+i 2pi tau*512/M}
            vi[r] = sin_rev(sv);
            float r0 = fract_f(tv * fm0);
            float c0 = cos_rev(r0), s0 = sin_rev(r0);
            uwr[r] = w * c0;                          // uw = w * e^{+i 2pi tau*m0/M}
            uwi[r] = w * s0;
        }
        const float2* hp = g_Hft + d * M_COLS + m0;
        #pragma unroll
        for (int j = 0; j < T_PTS; ++j) {
            float2 h = hp[j * M_STRIDE];              // coalesced, L2-resident
            #pragma unroll
            for (int r = 0; r < R_ROWS; ++r) {
                acc[r][j] = fmaf(uwr[r], h.x, fmaf(uwi[r], h.y, acc[r][j]));
                float nr = fmaf(uwr[r], vr[r], -(uwi[r] * vi[r]));  // uw *= v
                uwi[r]   = fmaf(uwr[r], vi[r],   uwi[r] * vr[r]);
                uwr[r]   = nr;
            }
        }
    }

    #pragma unroll
    for (int r = 0; r < R_ROWS; ++r) {
        float* op = out + (n0 + r) * M_COLS + m0;
        #pragma unroll
        for (int j = 0; j < T_PTS; ++j)
            op[j * M_STRIDE] = acc[r][j];
    }
}

extern "C" void kernel_launch(void* const* d_in, const int* in_sizes, int n_in,
                              void* d_out, int out_size, void* d_ws, size_t ws_size,
                              hipStream_t stream) {
    const float* W   = (const float*)d_in[0];   // [1024, 8]
    const float* H   = (const float*)d_in[1];   // [8, 4096]
    const float* tau = (const float*)d_in[2];   // [1024, 8]

    fft_fused<<<dim3(RANK * 16), dim3(256), 0, stream>>>(H, W);

    dim3 grid(M_COLS / (256 * T_PTS), N_ROWS / R_ROWS);  // (2, 512)
    shiftnmf_main<<<grid, dim3(256), 0, stream>>>(tau, (float*)d_out);
}